// Round 1
// baseline (235.264 us; speedup 1.0000x reference)
//
#include <hip/hip_runtime.h>

#define IN_F 1024
#define OUT_F 1024
#define RANK 4
#define SCALING 0.25f
#define WAVES_PER_BLOCK 4
#define ROWS_PER_WAVE 8

// One wave per row-group. Each lane register-caches its A fragment (RANK x 4
// float4, the K-slices this lane dots) and B fragment (16 B-rows as float4,
// the output elems this lane writes) once, then streams ROWS_PER_WAVE rows:
//   load x row (coalesced float4) -> rank-4 partial dots -> wave butterfly
//   reduce -> per-lane 16-output expansion -> coalesced float4 store.
// ~200 VGPRs -> 2 waves/EU; manual next-row x prefetch covers HBM latency.
__global__ __launch_bounds__(256, 2) void lora_fused(
    const float* __restrict__ x, const float* __restrict__ A,
    const float* __restrict__ B, float* __restrict__ out, int nrows) {
  const int lane = threadIdx.x & 63;
  const int wave = threadIdx.x >> 6;
  const int wave_id = blockIdx.x * WAVES_PER_BLOCK + wave;
  const int row0 = wave_id * ROWS_PER_WAVE;
  if (row0 >= nrows) return;

  // A: [RANK][IN_F] row-major -> float4 view [RANK][256].
  // Lane covers float4 indices lane + w*64, w=0..3.
  const float4* __restrict__ A4 = (const float4*)A;
  float4 af[RANK][4];
#pragma unroll
  for (int r = 0; r < RANK; ++r)
#pragma unroll
    for (int w = 0; w < 4; ++w)
      af[r][w] = A4[r * 256 + w * 64 + lane];

  // B: [OUT_F][RANK] row-major -> B4[o] = {B[o,0..3]}.
  // Lane writes output float4 indices (w*64 + lane), i.e. elems 4*(w*64+lane)+j.
  const float4* __restrict__ B4 = (const float4*)B;
  float4 bf[4][4];
#pragma unroll
  for (int w = 0; w < 4; ++w)
#pragma unroll
    for (int j = 0; j < 4; ++j)
      bf[w][j] = B4[4 * (w * 64 + lane) + j];

  // Prefetch first row.
  float4 xv[4];
  {
    const float4* __restrict__ x4 = (const float4*)(x + (size_t)row0 * IN_F);
#pragma unroll
    for (int w = 0; w < 4; ++w) xv[w] = x4[w * 64 + lane];
  }

#pragma unroll 1
  for (int i = 0; i < ROWS_PER_WAVE; ++i) {
    const int row = row0 + i;
    if (row >= nrows) break;

    // Prefetch next row while computing this one.
    float4 xn[4];
    const bool have_next = (i + 1 < ROWS_PER_WAVE) && (row + 1 < nrows);
    if (have_next) {
      const float4* __restrict__ x4n =
          (const float4*)(x + (size_t)(row + 1) * IN_F);
#pragma unroll
      for (int w = 0; w < 4; ++w) xn[w] = x4n[w * 64 + lane];
    }

    // h[r] = dot(x_row, A_row_r) partials over this lane's 16 elements.
    float h[RANK];
#pragma unroll
    for (int r = 0; r < RANK; ++r) h[r] = 0.0f;
#pragma unroll
    for (int r = 0; r < RANK; ++r)
#pragma unroll
      for (int w = 0; w < 4; ++w)
        h[r] += xv[w].x * af[r][w].x + xv[w].y * af[r][w].y +
                xv[w].z * af[r][w].z + xv[w].w * af[r][w].w;

    // 64-lane butterfly reduction.
#pragma unroll
    for (int off = 32; off > 0; off >>= 1)
#pragma unroll
      for (int r = 0; r < RANK; ++r) h[r] += __shfl_xor(h[r], off, 64);

#pragma unroll
    for (int r = 0; r < RANK; ++r) h[r] *= SCALING;

    // Expand: out[o] = sum_r h[r] * B[o][r], 16 elems per lane, coalesced.
    float4* __restrict__ out4 = (float4*)(out + (size_t)row * OUT_F);
#pragma unroll
    for (int w = 0; w < 4; ++w) {
      float4 res;
      res.x = h[0] * bf[w][0].x + h[1] * bf[w][0].y + h[2] * bf[w][0].z +
              h[3] * bf[w][0].w;
      res.y = h[0] * bf[w][1].x + h[1] * bf[w][1].y + h[2] * bf[w][1].z +
              h[3] * bf[w][1].w;
      res.z = h[0] * bf[w][2].x + h[1] * bf[w][2].y + h[2] * bf[w][2].z +
              h[3] * bf[w][2].w;
      res.w = h[0] * bf[w][3].x + h[1] * bf[w][3].y + h[2] * bf[w][3].z +
              h[3] * bf[w][3].w;
      out4[w * 64 + lane] = res;
    }

    if (have_next) {
#pragma unroll
      for (int w = 0; w < 4; ++w) xv[w] = xn[w];
    }
  }
}

extern "C" void kernel_launch(void* const* d_in, const int* in_sizes, int n_in,
                              void* d_out, int out_size, void* d_ws,
                              size_t ws_size, hipStream_t stream) {
  const float* x = (const float*)d_in[0];
  const float* A = (const float*)d_in[1];
  const float* B = (const float*)d_in[2];
  float* out = (float*)d_out;

  const int nrows = in_sizes[0] / IN_F;  // 4*8192 = 32768
  const int waves = (nrows + ROWS_PER_WAVE - 1) / ROWS_PER_WAVE;
  const int blocks = (waves + WAVES_PER_BLOCK - 1) / WAVES_PER_BLOCK;
  lora_fused<<<blocks, WAVES_PER_BLOCK * 64, 0, stream>>>(x, A, B, out, nrows);
}

// Round 2
// 234.921 us; speedup vs baseline: 1.0015x; 1.0015x over previous
//
#include <hip/hip_runtime.h>
#include <stdint.h>

#define IN_F 1024
#define OUT_F 1024
#define SCALING 0.25f
#define TILE_ROWS 16
#define CHUNK_COLS 256                 // floats per chunk per row
#define NCHUNK (IN_F / CHUNK_COLS)     // 4
#define ROW_PITCH 260                  // floats: 256 + 4 pad
#define BLOCK 256

typedef __attribute__((address_space(3))) unsigned int as3_u32;
typedef const __attribute__((address_space(1))) unsigned int as1_u32;

// Async DMA one 256-float row-chunk (1 KB) global -> LDS.
// LDS dest is wave-uniform base + lane*16 (contiguous row), per the HW rule.
__device__ __forceinline__ void row_to_lds(const float* g, const float* lds_row,
                                           int lane) {
  __builtin_amdgcn_global_load_lds(
      (as1_u32*)(uintptr_t)(g + lane * 4),
      (as3_u32*)(uint32_t)(uintptr_t)(lds_row),  // low 32 bits = LDS offset
      16, 0, 0);
}

// Two-phase LoRA tile kernel. Block = 256 threads = 4 waves, 16 rows/tile.
// Phase 1 (h = x@A^T): wave w owns rows 4w..4w+3; lane = (row = lane>>4,
//   seg = lane&15) accumulates rank-4 partials over its 16 cols/chunk from
//   LDS. Chunks are double-buffered via global_load_lds + manual vmcnt —
//   NO barriers in the K-loop (rows are wave-private). ONE 4-stage butterfly
//   per tile replaces R1's per-row 6-stage chain.
// Phase 2 (out = h@B^T * s): B-frag in regs, h broadcast from LDS,
//   coalesced float4 stores.
__global__ __launch_bounds__(BLOCK) void lora_tile(
    const float* __restrict__ x, const float* __restrict__ A,
    const float* __restrict__ B, float* __restrict__ out, int nrows) {
  __shared__ float4 As4[4 * 256];                  // 16 KB: A[rank][256 f4]
  __shared__ float xs[2][TILE_ROWS * ROW_PITCH];   // 2 x 16.6 KB x chunks
  __shared__ float4 hf[TILE_ROWS];                 // final h per row

  const int t = threadIdx.x;
  const int lane = t & 63;
  const int wave = t >> 6;
  const int row0 = blockIdx.x * TILE_ROWS;
  if (row0 >= nrows) return;

  // B fragment: thread t writes out float4 column t -> needs B rows 4t..4t+3.
  const float4* __restrict__ B4 = (const float4*)B;
  const float4 bf0 = B4[4 * t + 0];
  const float4 bf1 = B4[4 * t + 1];
  const float4 bf2 = B4[4 * t + 2];
  const float4 bf3 = B4[4 * t + 3];

  // Stage A into LDS (once per block; A is L2-hot across blocks).
  const float4* __restrict__ A4 = (const float4*)A;
#pragma unroll
  for (int k = 0; k < 4; ++k) As4[t + 256 * k] = A4[t + 256 * k];
  __syncthreads();  // drains everything; chunk-0 DMA issued after this

  // Issue chunk 0 into buffer 0 (4 rows per wave, 1 KB per call).
#pragma unroll
  for (int r = 0; r < 4; ++r) {
    const int row = wave * 4 + r;
    row_to_lds(x + (size_t)(row0 + row) * IN_F, &xs[0][row * ROW_PITCH], lane);
  }

  const int lrow = lane >> 4;        // 0..3 row within wave
  const int seg = lane & 15;         // 16-col segment within chunk
  const int myrow = wave * 4 + lrow; // 0..15 row within tile

  float h0 = 0.f, h1 = 0.f, h2 = 0.f, h3 = 0.f;

#pragma unroll
  for (int c = 0; c < NCHUNK; ++c) {
    if (c + 1 < NCHUNK) {
      // Prefetch next chunk, then wait for current (vmcnt<=4 leaves only the
      // 4 just-issued prefetches outstanding). A/x compute reads are LDS
      // (lgkmcnt), so vmcnt tracks ONLY these DMAs — count is exact.
#pragma unroll
      for (int r = 0; r < 4; ++r) {
        const int row = wave * 4 + r;
        row_to_lds(x + (size_t)(row0 + row) * IN_F + (c + 1) * CHUNK_COLS,
                   &xs[(c + 1) & 1][row * ROW_PITCH], lane);
      }
      __builtin_amdgcn_s_waitcnt(0xF74);  // vmcnt(4), expcnt/lgkm = max
    } else {
      __builtin_amdgcn_s_waitcnt(0xF70);  // vmcnt(0)
    }
    __asm__ __volatile__("" ::: "memory");  // no LDS-read hoisting above wait

    const float4* __restrict__ xr4 =
        (const float4*)&xs[c & 1][myrow * ROW_PITCH + seg * 16];
#pragma unroll
    for (int j = 0; j < 4; ++j) {
      const float4 xv = xr4[j];
      const int ai = c * 64 + seg * 4 + j;
      const float4 a0 = As4[0 * 256 + ai];
      const float4 a1 = As4[1 * 256 + ai];
      const float4 a2 = As4[2 * 256 + ai];
      const float4 a3 = As4[3 * 256 + ai];
      h0 += xv.x * a0.x + xv.y * a0.y + xv.z * a0.z + xv.w * a0.w;
      h1 += xv.x * a1.x + xv.y * a1.y + xv.z * a1.z + xv.w * a1.w;
      h2 += xv.x * a2.x + xv.y * a2.y + xv.z * a2.z + xv.w * a2.w;
      h3 += xv.x * a3.x + xv.y * a3.y + xv.z * a3.z + xv.w * a3.w;
    }
  }

  // One 4-stage butterfly per tile: reduce across the 16 lanes of each row.
#pragma unroll
  for (int off = 1; off < 16; off <<= 1) {
    h0 += __shfl_xor(h0, off, 64);
    h1 += __shfl_xor(h1, off, 64);
    h2 += __shfl_xor(h2, off, 64);
    h3 += __shfl_xor(h3, off, 64);
  }
  if (seg == 0)
    hf[myrow] = make_float4(h0 * SCALING, h1 * SCALING, h2 * SCALING,
                            h3 * SCALING);
  __syncthreads();

  // Phase 2: expand 16 rows x 1024 cols, fully coalesced float4 stores.
  float4* __restrict__ out4 = (float4*)out;
#pragma unroll
  for (int r = 0; r < TILE_ROWS; ++r) {
    const float4 h = hf[r];  // same addr all lanes -> LDS broadcast
    float4 res;
    res.x = h.x * bf0.x + h.y * bf0.y + h.z * bf0.z + h.w * bf0.w;
    res.y = h.x * bf1.x + h.y * bf1.y + h.z * bf1.z + h.w * bf1.w;
    res.z = h.x * bf2.x + h.y * bf2.y + h.z * bf2.z + h.w * bf2.w;
    res.w = h.x * bf3.x + h.y * bf3.y + h.z * bf3.z + h.w * bf3.w;
    out4[(size_t)(row0 + r) * (OUT_F / 4) + t] = res;
  }
}

extern "C" void kernel_launch(void* const* d_in, const int* in_sizes, int n_in,
                              void* d_out, int out_size, void* d_ws,
                              size_t ws_size, hipStream_t stream) {
  const float* x = (const float*)d_in[0];
  const float* A = (const float*)d_in[1];
  const float* B = (const float*)d_in[2];
  float* out = (float*)d_out;

  const int nrows = in_sizes[0] / IN_F;  // 32768
  const int blocks = (nrows + TILE_ROWS - 1) / TILE_ROWS;  // 2048
  lora_tile<<<blocks, BLOCK, 0, stream>>>(x, A, B, out, nrows);
}